// Round 1
// baseline (104.386 us; speedup 1.0000x reference)
//
#include <hip/hip_runtime.h>

#define TI 256
#define TJ 256

__global__ __launch_bounds__(256) void cindex_pairs_kernel(
    const float* __restrict__ risk,
    const float* __restrict__ tim,
    const int*   __restrict__ evt,
    unsigned long long* __restrict__ acc,
    int n)
{
    const int i0 = blockIdx.x * TI;
    const int j0 = blockIdx.y * TJ;

    // Tile contributes only if some j > i exists: max j = j0+TJ-1 must exceed min i = i0.
    if (j0 + TJ - 1 <= i0) return;

    __shared__ float s_t[TJ];
    __shared__ float s_r[TJ];
    __shared__ int   s_e[TJ];

    const int tid = threadIdx.x;
    {
        int j = j0 + tid;
        if (j < n) {
            s_t[tid] = tim[j];
            s_r[tid] = risk[j];
            s_e[tid] = evt[j];
        } else {
            s_t[tid] = 0.0f; s_r[tid] = 0.0f; s_e[tid] = -1; // never matches
        }
    }
    __syncthreads();

    int nComp = 0, nConc = 0, nTie = 0;

    const int i = i0 + tid;
    if (i < n && evt[i] == 1) {
        const float ti = tim[i];
        const float ri = risk[i];
        // j must satisfy j > i within [j0, j0+TJ)
        int jj_start = (i + 1 > j0) ? (i + 1 - j0) : 0;
        // Padding lanes (j >= n) were loaded with s_e = -1 and ti<tj false etc.
        for (int jj = jj_start; jj < TJ; ++jj) {
            float tj = s_t[jj];
            float rj = s_r[jj];
            int   ejv = s_e[jj];
            bool ej = (ejv == 1);
            bool ej0 = (ejv == 0);
            bool lt = ti < tj;
            bool gt = ti > tj;
            bool rgt = ri > rj;
            bool rlt = ri < rj;
            bool req = ri == rj;
            bool comp = ej || (ej0 && lt);
            bool conc = ej ? ((lt && rgt) || (gt && rlt)) : (ej0 && lt && rgt);
            nComp += comp ? 1 : 0;
            nConc += conc ? 1 : 0;
            nTie  += (comp && req) ? 1 : 0;
        }
    }

    // wave (64-lane) shuffle reduction
    for (int off = 32; off > 0; off >>= 1) {
        nComp += __shfl_down(nComp, off, 64);
        nConc += __shfl_down(nConc, off, 64);
        nTie  += __shfl_down(nTie,  off, 64);
    }

    const int lane = tid & 63;
    if (lane == 0) {
        atomicAdd(&acc[0], (unsigned long long)nConc);
        atomicAdd(&acc[1], (unsigned long long)nTie);
        atomicAdd(&acc[2], (unsigned long long)nComp);
    }
}

__global__ void cindex_final_kernel(const unsigned long long* __restrict__ acc,
                                    float* __restrict__ out)
{
    double conc = (double)acc[0];
    double tie  = (double)acc[1];
    double comp = (double)acc[2];
    float c;
    if (comp > 0.0) {
        c = (float)((conc + 0.5 * tie) / comp);
    } else {
        c = 0.5f;
    }
    out[0] = 1.0f - c;
}

extern "C" void kernel_launch(void* const* d_in, const int* in_sizes, int n_in,
                              void* d_out, int out_size, void* d_ws, size_t ws_size,
                              hipStream_t stream)
{
    const float* risk = (const float*)d_in[0];   // (B,1) f32, flat B
    const float* tim  = (const float*)d_in[1];   // (B,)  f32
    const int*   evt  = (const int*)d_in[2];     // (B,)  i32
    float* out = (float*)d_out;
    unsigned long long* acc = (unsigned long long*)d_ws;

    const int n = in_sizes[1]; // B from time array

    hipMemsetAsync(d_ws, 0, 3 * sizeof(unsigned long long), stream);

    dim3 grid((n + TI - 1) / TI, (n + TJ - 1) / TJ);
    cindex_pairs_kernel<<<grid, 256, 0, stream>>>(risk, tim, evt, acc, n);
    cindex_final_kernel<<<1, 1, 0, stream>>>(acc, out);
}

// Round 2
// 89.076 us; speedup vs baseline: 1.1719x; 1.1719x over previous
//
#include <hip/hip_runtime.h>

#define TI 64    // i rows staged in LDS per block (== wave width, ballot-friendly)
#define TJ 256   // j columns, one per thread

__global__ __launch_bounds__(256) void cindex_pairs_kernel(
    const float* __restrict__ risk,
    const float* __restrict__ tim,
    const int*   __restrict__ evt,
    unsigned int* __restrict__ acc,
    int n)
{
    const int i0 = blockIdx.y * TI;
    const int j0 = blockIdx.x * TJ;
    // Need some j > i: max j = j0+TJ-1 must exceed min i = i0.
    if (j0 + TJ - 1 <= i0) return;

    __shared__ float s_t[TI];
    __shared__ float s_r[TI];
    __shared__ unsigned int s_mlo, s_mhi;
    __shared__ unsigned int s_part[4][3];

    const int tid = threadIdx.x;

    // Wave 0 stages the i-tile and builds the event bitmask (TI == 64 == wave).
    if (tid < TI) {
        int i = i0 + tid;
        bool inb = (i < n);
        s_t[tid] = inb ? tim[i]  : 0.0f;
        s_r[tid] = inb ? risk[i] : 0.0f;
        unsigned long long m = __ballot(inb && (evt[i] == 1));
        if (tid == 0) { s_mlo = (unsigned int)m; s_mhi = (unsigned int)(m >> 32); }
    }
    __syncthreads();

    // Force the event mask into SGPRs so the i-loop is scalar-controlled.
    unsigned int mlo = __builtin_amdgcn_readfirstlane((int)s_mlo);
    unsigned int mhi = __builtin_amdgcn_readfirstlane((int)s_mhi);
    unsigned long long em = (((unsigned long long)mhi) << 32) | (unsigned long long)mlo;

    // Per-lane j data, resident in registers for the whole loop.
    const int j  = j0 + tid;
    const bool jv = (j < n);
    const float tj = jv ? tim[j]  : 0.0f;
    const float rj = jv ? risk[j] : 0.0f;
    const int  ejv = jv ? evt[j]  : -1;
    const bool ej1 = (ejv == 1);
    const bool ej0 = (ejv == 0);

    unsigned int nComp = 0, nConc = 0, nTie = 0;

    if (j0 >= i0 + TI) {
        // Off-diagonal tile: every staged i < every j — no per-pair j>i check.
        while (em) {
            int ii = __builtin_ctzll(em); em &= (em - 1);
            float ti = s_t[ii];
            float ri = s_r[ii];
            bool lt  = ti < tj;
            bool gt  = ti > tj;
            bool rgt = ri > rj;
            bool rlt = ri < rj;
            bool req = ri == rj;
            bool comp = ej1 | (ej0 & lt);
            bool conc = (ej1 & ((lt & rgt) | (gt & rlt))) | (ej0 & lt & rgt);
            nComp += (unsigned int)comp;
            nConc += (unsigned int)conc;
            nTie  += (unsigned int)(comp & req);
        }
    } else {
        // Overlapping tile: enforce strict upper-triangle j > i per pair.
        while (em) {
            int ii = __builtin_ctzll(em); em &= (em - 1);
            float ti = s_t[ii];
            float ri = s_r[ii];
            bool ok  = j > (i0 + ii);
            bool lt  = ti < tj;
            bool gt  = ti > tj;
            bool rgt = ri > rj;
            bool rlt = ri < rj;
            bool req = ri == rj;
            bool comp = (ej1 | (ej0 & lt)) & ok;
            bool conc = ((ej1 & ((lt & rgt) | (gt & rlt))) | (ej0 & lt & rgt)) & ok;
            nComp += (unsigned int)comp;
            nConc += (unsigned int)conc;
            nTie  += (unsigned int)(comp & req);
        }
    }

    // Wave-level shuffle reduction (64 lanes).
    for (int off = 32; off > 0; off >>= 1) {
        nComp += __shfl_down(nComp, off, 64);
        nConc += __shfl_down(nConc, off, 64);
        nTie  += __shfl_down(nTie,  off, 64);
    }
    const int wid  = tid >> 6;
    const int lane = tid & 63;
    if (lane == 0) {
        s_part[wid][0] = nConc;
        s_part[wid][1] = nTie;
        s_part[wid][2] = nComp;
    }
    __syncthreads();
    if (tid == 0) {
        unsigned int c0 = 0, c1 = 0, c2 = 0;
        #pragma unroll
        for (int w = 0; w < 4; ++w) {
            c0 += s_part[w][0];
            c1 += s_part[w][1];
            c2 += s_part[w][2];
        }
        atomicAdd(&acc[0], c0);
        atomicAdd(&acc[1], c1);
        atomicAdd(&acc[2], c2);
    }
}

__global__ void cindex_final_kernel(const unsigned int* __restrict__ acc,
                                    float* __restrict__ out)
{
    double conc = (double)acc[0];
    double tie  = (double)acc[1];
    double comp = (double)acc[2];
    float c;
    if (comp > 0.0) {
        c = (float)((conc + 0.5 * tie) / comp);
    } else {
        c = 0.5f;
    }
    out[0] = 1.0f - c;
}

extern "C" void kernel_launch(void* const* d_in, const int* in_sizes, int n_in,
                              void* d_out, int out_size, void* d_ws, size_t ws_size,
                              hipStream_t stream)
{
    const float* risk = (const float*)d_in[0];   // (B,1) f32, flat B
    const float* tim  = (const float*)d_in[1];   // (B,)  f32
    const int*   evt  = (const int*)d_in[2];     // (B,)  i32
    float* out = (float*)d_out;
    unsigned int* acc = (unsigned int*)d_ws;

    const int n = in_sizes[1];

    hipMemsetAsync(d_ws, 0, 3 * sizeof(unsigned int), stream);

    dim3 grid((n + TJ - 1) / TJ, (n + TI - 1) / TI);
    cindex_pairs_kernel<<<grid, 256, 0, stream>>>(risk, tim, evt, acc, n);
    cindex_final_kernel<<<1, 1, 0, stream>>>(acc, out);
}

// Round 3
// 27.207 us; speedup vs baseline: 3.8367x; 3.2740x over previous
//
#include <hip/hip_runtime.h>

#define TI 64    // i rows staged in LDS per block (== wave width, ballot-friendly)
#define TJ 256   // j columns, one per thread

__global__ __launch_bounds__(256) void cindex_pairs_kernel(
    const float* __restrict__ risk,
    const float* __restrict__ tim,
    const int*   __restrict__ evt,
    unsigned int* __restrict__ part,   // SoA: [0,nblk)=conc, [nblk,2n)=tie, [2n,3n)=comp
    int n, int nblk)
{
    const int bid = blockIdx.y * gridDim.x + blockIdx.x;
    const int i0 = blockIdx.y * TI;
    const int j0 = blockIdx.x * TJ;
    const int tid = threadIdx.x;

    // Inactive tile (entirely below diagonal): write zero partials (d_ws is
    // poisoned once, never re-poisoned — every slot must be written).
    if (j0 + TJ - 1 <= i0) {
        if (tid == 0) {
            part[bid] = 0u;
            part[nblk + bid] = 0u;
            part[2 * nblk + bid] = 0u;
        }
        return;
    }

    __shared__ float s_t[TI];
    __shared__ float s_r[TI];
    __shared__ unsigned int s_mlo, s_mhi;
    __shared__ unsigned int s_part[4][3];

    // Wave 0 stages the i-tile and builds the event bitmask (TI == 64 == wave).
    if (tid < TI) {
        int i = i0 + tid;
        bool inb = (i < n);
        s_t[tid] = inb ? tim[i]  : 0.0f;
        s_r[tid] = inb ? risk[i] : 0.0f;
        unsigned long long m = __ballot(inb && (evt[i] == 1));
        if (tid == 0) { s_mlo = (unsigned int)m; s_mhi = (unsigned int)(m >> 32); }
    }
    __syncthreads();

    // Force the event mask into SGPRs so the i-loop is scalar-controlled.
    unsigned int mlo = __builtin_amdgcn_readfirstlane((int)s_mlo);
    unsigned int mhi = __builtin_amdgcn_readfirstlane((int)s_mhi);
    unsigned long long em = (((unsigned long long)mhi) << 32) | (unsigned long long)mlo;

    // Per-lane j data, resident in registers for the whole loop.
    const int j  = j0 + tid;
    const bool jv = (j < n);
    const float tj = jv ? tim[j]  : 0.0f;
    const float rj = jv ? risk[j] : 0.0f;
    const int  ejv = jv ? evt[j]  : -1;
    const bool ej1 = (ejv == 1);
    const bool ej0 = (ejv == 0);

    unsigned int nComp = 0, nConc = 0, nTie = 0;

    if (j0 >= i0 + TI) {
        // Off-diagonal tile: every staged i < every j — no per-pair j>i check.
        while (em) {
            int ii = __builtin_ctzll(em); em &= (em - 1);
            float ti = s_t[ii];
            float ri = s_r[ii];
            bool lt  = ti < tj;
            bool gt  = ti > tj;
            bool rgt = ri > rj;
            bool rlt = ri < rj;
            bool req = ri == rj;
            bool comp = ej1 | (ej0 & lt);
            bool conc = (ej1 & ((lt & rgt) | (gt & rlt))) | (ej0 & lt & rgt);
            nComp += (unsigned int)comp;
            nConc += (unsigned int)conc;
            nTie  += (unsigned int)(comp & req);
        }
    } else {
        // Overlapping tile: enforce strict upper-triangle j > i per pair.
        while (em) {
            int ii = __builtin_ctzll(em); em &= (em - 1);
            float ti = s_t[ii];
            float ri = s_r[ii];
            bool ok  = j > (i0 + ii);
            bool lt  = ti < tj;
            bool gt  = ti > tj;
            bool rgt = ri > rj;
            bool rlt = ri < rj;
            bool req = ri == rj;
            bool comp = (ej1 | (ej0 & lt)) & ok;
            bool conc = ((ej1 & ((lt & rgt) | (gt & rlt))) | (ej0 & lt & rgt)) & ok;
            nComp += (unsigned int)comp;
            nConc += (unsigned int)conc;
            nTie  += (unsigned int)(comp & req);
        }
    }

    // Wave-level shuffle reduction (64 lanes).
    for (int off = 32; off > 0; off >>= 1) {
        nComp += __shfl_down(nComp, off, 64);
        nConc += __shfl_down(nConc, off, 64);
        nTie  += __shfl_down(nTie,  off, 64);
    }
    const int wid  = tid >> 6;
    const int lane = tid & 63;
    if (lane == 0) {
        s_part[wid][0] = nConc;
        s_part[wid][1] = nTie;
        s_part[wid][2] = nComp;
    }
    __syncthreads();
    if (tid == 0) {
        unsigned int c0 = 0, c1 = 0, c2 = 0;
        #pragma unroll
        for (int w = 0; w < 4; ++w) {
            c0 += s_part[w][0];
            c1 += s_part[w][1];
            c2 += s_part[w][2];
        }
        part[bid] = c0;                // conc
        part[nblk + bid] = c1;         // tie
        part[2 * nblk + bid] = c2;     // comp
    }
}

__global__ __launch_bounds__(256) void cindex_reduce_kernel(
    const unsigned int* __restrict__ part,
    float* __restrict__ out, int nblk)
{
    const int tid = threadIdx.x;
    unsigned int c0 = 0, c1 = 0, c2 = 0;
    for (int i = tid; i < nblk; i += 256) {
        c0 += part[i];
        c1 += part[nblk + i];
        c2 += part[2 * nblk + i];
    }
    for (int off = 32; off > 0; off >>= 1) {
        c0 += __shfl_down(c0, off, 64);
        c1 += __shfl_down(c1, off, 64);
        c2 += __shfl_down(c2, off, 64);
    }
    __shared__ unsigned int s_part[4][3];
    const int wid  = tid >> 6;
    const int lane = tid & 63;
    if (lane == 0) {
        s_part[wid][0] = c0;
        s_part[wid][1] = c1;
        s_part[wid][2] = c2;
    }
    __syncthreads();
    if (tid == 0) {
        unsigned int t0 = 0, t1 = 0, t2 = 0;
        #pragma unroll
        for (int w = 0; w < 4; ++w) {
            t0 += s_part[w][0];
            t1 += s_part[w][1];
            t2 += s_part[w][2];
        }
        double conc = (double)t0;
        double tie  = (double)t1;
        double comp = (double)t2;
        float c;
        if (comp > 0.0) {
            c = (float)((conc + 0.5 * tie) / comp);
        } else {
            c = 0.5f;
        }
        out[0] = 1.0f - c;
    }
}

extern "C" void kernel_launch(void* const* d_in, const int* in_sizes, int n_in,
                              void* d_out, int out_size, void* d_ws, size_t ws_size,
                              hipStream_t stream)
{
    const float* risk = (const float*)d_in[0];   // (B,1) f32, flat B
    const float* tim  = (const float*)d_in[1];   // (B,)  f32
    const int*   evt  = (const int*)d_in[2];     // (B,)  i32
    float* out = (float*)d_out;
    unsigned int* part = (unsigned int*)d_ws;

    const int n = in_sizes[1];

    dim3 grid((n + TJ - 1) / TJ, (n + TI - 1) / TI);
    const int nblk = grid.x * grid.y;

    cindex_pairs_kernel<<<grid, 256, 0, stream>>>(risk, tim, evt, part, n, nblk);
    cindex_reduce_kernel<<<1, 256, 0, stream>>>(part, out, nblk);
}

// Round 4
// 25.741 us; speedup vs baseline: 4.0552x; 1.0570x over previous
//
#include <hip/hip_runtime.h>

#define TILE 256   // square tile side; block = 256 threads, j per-lane

__global__ __launch_bounds__(256) void cindex_pairs_kernel(
    const float* __restrict__ risk,
    const float* __restrict__ tim,
    const int*   __restrict__ evt,
    unsigned int* __restrict__ part,   // SoA: [0,nblk)=conc, [nblk,2n)=tie, [2n,3n)=comp
    int n, int nblk)
{
    const int t = blockIdx.x;
    // Decode lower-triangle pair (p >= q): p*(p+1)/2 <= t < (p+1)*(p+2)/2
    int p = (int)((sqrtf(8.0f * (float)t + 1.0f) - 1.0f) * 0.5f);
    while ((p + 1) * (p + 2) / 2 <= t) ++p;
    while (p * (p + 1) / 2 > t) --p;
    const int q = t - p * (p + 1) / 2;

    const int i0 = q * TILE;          // i-tile (smaller index)
    const int j0 = p * TILE;          // j-tile (larger index)
    const bool diag = (p == q);

    __shared__ float s_t[TILE];
    __shared__ float s_r[TILE];
    __shared__ unsigned int s_mask[4][2];
    __shared__ unsigned int s_part[4][3];

    const int tid = threadIdx.x;

    // Stage the i-tile; build one 64-bit event mask per wave.
    {
        int i = i0 + tid;
        bool inb = (i < n);
        s_t[tid] = inb ? tim[i]  : 0.0f;
        s_r[tid] = inb ? risk[i] : 0.0f;
        unsigned long long m = __ballot(inb && (evt[i] == 1));
        if ((tid & 63) == 0) {
            s_mask[tid >> 6][0] = (unsigned int)m;
            s_mask[tid >> 6][1] = (unsigned int)(m >> 32);
        }
    }
    __syncthreads();

    // Per-lane j data, register-resident for the whole block.
    const int j  = j0 + tid;
    const bool jv = (j < n);
    const float tj = jv ? tim[j]  : 0.0f;
    const float rj = jv ? risk[j] : 0.0f;
    const int  ejv = jv ? evt[j]  : -1;
    const bool ej1 = (ejv == 1);
    const bool ej0 = (ejv == 0);

    unsigned int nComp = 0, nConc = 0, nTie = 0;

    #pragma unroll
    for (int s = 0; s < 4; ++s) {
        // Broadcast this sub-tile's event mask into SGPRs (scalar loop control).
        unsigned int lo = __builtin_amdgcn_readfirstlane((int)s_mask[s][0]);
        unsigned int hi = __builtin_amdgcn_readfirstlane((int)s_mask[s][1]);
        unsigned long long em = (((unsigned long long)hi) << 32) | (unsigned long long)lo;
        const int ibase = s * 64;

        if (!diag) {
            // Off-diagonal: every staged i < every j (j0 >= i0+TILE).
            while (em) {
                int ii = __builtin_ctzll(em); em &= (em - 1);
                float ti = s_t[ibase + ii];
                float ri = s_r[ibase + ii];
                bool lt  = ti < tj;
                bool gt  = ti > tj;
                bool rgt = ri > rj;
                bool rlt = ri < rj;
                bool req = ri == rj;
                bool comp = ej1 | (ej0 & lt);
                bool conc = (ej1 & ((lt & rgt) | (gt & rlt))) | (ej0 & lt & rgt);
                nComp += (unsigned int)comp;
                nConc += (unsigned int)conc;
                nTie  += (unsigned int)(comp & req);
            }
        } else {
            // Diagonal tile: j0 == i0, enforce j > i  <=>  tid > ibase+ii.
            while (em) {
                int ii = __builtin_ctzll(em); em &= (em - 1);
                float ti = s_t[ibase + ii];
                float ri = s_r[ibase + ii];
                bool ok  = tid > (ibase + ii);
                bool lt  = ti < tj;
                bool gt  = ti > tj;
                bool rgt = ri > rj;
                bool rlt = ri < rj;
                bool req = ri == rj;
                bool comp = (ej1 | (ej0 & lt)) & ok;
                bool conc = ((ej1 & ((lt & rgt) | (gt & rlt))) | (ej0 & lt & rgt)) & ok;
                nComp += (unsigned int)comp;
                nConc += (unsigned int)conc;
                nTie  += (unsigned int)(comp & req);
            }
        }
    }

    // Wave-level shuffle reduction (64 lanes).
    for (int off = 32; off > 0; off >>= 1) {
        nComp += __shfl_down(nComp, off, 64);
        nConc += __shfl_down(nConc, off, 64);
        nTie  += __shfl_down(nTie,  off, 64);
    }
    const int wid  = tid >> 6;
    const int lane = tid & 63;
    if (lane == 0) {
        s_part[wid][0] = nConc;
        s_part[wid][1] = nTie;
        s_part[wid][2] = nComp;
    }
    __syncthreads();
    if (tid == 0) {
        unsigned int c0 = 0, c1 = 0, c2 = 0;
        #pragma unroll
        for (int w = 0; w < 4; ++w) {
            c0 += s_part[w][0];
            c1 += s_part[w][1];
            c2 += s_part[w][2];
        }
        part[t] = c0;                // conc
        part[nblk + t] = c1;         // tie
        part[2 * nblk + t] = c2;     // comp
    }
}

__global__ __launch_bounds__(256) void cindex_reduce_kernel(
    const unsigned int* __restrict__ part,
    float* __restrict__ out, int nblk)
{
    const int tid = threadIdx.x;
    unsigned int c0 = 0, c1 = 0, c2 = 0;
    for (int i = tid; i < nblk; i += 256) {
        c0 += part[i];
        c1 += part[nblk + i];
        c2 += part[2 * nblk + i];
    }
    for (int off = 32; off > 0; off >>= 1) {
        c0 += __shfl_down(c0, off, 64);
        c1 += __shfl_down(c1, off, 64);
        c2 += __shfl_down(c2, off, 64);
    }
    __shared__ unsigned int s_part[4][3];
    const int wid  = tid >> 6;
    const int lane = tid & 63;
    if (lane == 0) {
        s_part[wid][0] = c0;
        s_part[wid][1] = c1;
        s_part[wid][2] = c2;
    }
    __syncthreads();
    if (tid == 0) {
        unsigned int t0 = 0, t1 = 0, t2 = 0;
        #pragma unroll
        for (int w = 0; w < 4; ++w) {
            t0 += s_part[w][0];
            t1 += s_part[w][1];
            t2 += s_part[w][2];
        }
        double conc = (double)t0;
        double tie  = (double)t1;
        double comp = (double)t2;
        float c;
        if (comp > 0.0) {
            c = (float)((conc + 0.5 * tie) / comp);
        } else {
            c = 0.5f;
        }
        out[0] = 1.0f - c;
    }
}

extern "C" void kernel_launch(void* const* d_in, const int* in_sizes, int n_in,
                              void* d_out, int out_size, void* d_ws, size_t ws_size,
                              hipStream_t stream)
{
    const float* risk = (const float*)d_in[0];   // (B,1) f32, flat B
    const float* tim  = (const float*)d_in[1];   // (B,)  f32
    const int*   evt  = (const int*)d_in[2];     // (B,)  i32
    float* out = (float*)d_out;
    unsigned int* part = (unsigned int*)d_ws;

    const int n = in_sizes[1];
    const int nt = (n + TILE - 1) / TILE;        // tile rows (32 for n=8192)
    const int nblk = nt * (nt + 1) / 2;          // triangular tile count (528)

    cindex_pairs_kernel<<<dim3(nblk), 256, 0, stream>>>(risk, tim, evt, part, n, nblk);
    cindex_reduce_kernel<<<1, 256, 0, stream>>>(part, out, nblk);
}